// Round 6
// baseline (1692.076 us; speedup 1.0000x reference)
//
#include <hip/hip_runtime.h>
#include <hip/hip_bf16.h>

typedef __attribute__((ext_vector_type(8))) short s8v;
typedef __attribute__((ext_vector_type(4))) short s4v;
typedef __attribute__((ext_vector_type(4))) float f4v;

#define B_   32
#define S_   256
#define H_   300
#define HP   320
#define NW   19
#define TAGS 9

// workspace layout (~14.9 MB; proven >=16.3 MB writable)
#define XS_OFF    0                      // bf16 staged embeddings: 256*32*320*2 = 5242880 B
#define HB_OFF    5242880                // bf16 h ping-pong: 2dir*2slot*32*320*2 = 81920 B
#define HIST_OFF  5324800                // bf16 h history: 256*32*608*2 = 9961472 B
#define EM_OFF    15286272               // fp32 emissions: 256*32*9*4 = 294912 B
#define EMTAG_OFF 15581184               // fp32: 256*32*4 = 32768 B
#define ARR_OFF   15613952               // per-WG flags: 2*NW*16 ints (64B apart)

#define LOSS_IDX  ((long)B_*S_*TAGS)     // float element 73728

__device__ __forceinline__ short f2b(float f) {
  unsigned int u = __builtin_bit_cast(unsigned int, f);
  u = (u + 0x7FFFu + ((u >> 16) & 1u)) >> 16;      // RNE fp32 -> bf16
  return (short)u;
}
__device__ __forceinline__ float b2f(unsigned int lo16) {
  return __builtin_bit_cast(float, lo16 << 16);
}
__device__ __forceinline__ float sigf(float x) { return 1.f / (1.f + __expf(-x)); }
__device__ __forceinline__ float tanh_f(float x) {
  x = fminf(fmaxf(x, -15.f), 15.f);
  float e = __expf(-2.f * x);
  return (1.f - e) / (1.f + e);
}

// ---- init: gather emb->bf16 xs (padded K 320), zero h ping-pong + flags ----
__global__ void k_init(const int* __restrict__ x, const float* __restrict__ emb,
                       char* __restrict__ ws) {
  short* xs = (short*)(ws + XS_OFF);
  short* hb = (short*)(ws + HB_OFF);
  int* arr  = (int*)(ws + ARR_OFF);
  long u = (long)blockIdx.x * blockDim.x + threadIdx.x;
  const long N1 = (long)S_ * B_ * 80;              // s4v units of xs
  if (u < N1) {
    int kg = (int)(u % 80);
    long tb = u / 80;
    int b = (int)(tb % B_);
    int t = (int)(tb / B_);
    int k = kg * 4;
    s4v v; v[0]=0; v[1]=0; v[2]=0; v[3]=0;
    if (k + 4 <= H_) {                             // emb rows are 16B aligned (300%4==0)
      int row = x[b * S_ + t];
      f4v q = *(const f4v*)(emb + (long)row * H_ + k);
      v[0]=f2b(q[0]); v[1]=f2b(q[1]); v[2]=f2b(q[2]); v[3]=f2b(q[3]);
    }
    *(s4v*)(xs + ((long)t * B_ + b) * HP + k) = v;
    return;
  }
  u -= N1;
  const long N2 = 2L * 2 * B_ * HP / 4;            // s4v units of hb
  if (u < N2) {
    s4v z; z[0]=0; z[1]=0; z[2]=0; z[3]=0;
    *(s4v*)(hb + u * 4) = z;
    return;
  }
  u -= N2;
  if (u < 2L*NW*16) arr[u] = 0;
}

// ---- persistent BiLSTM recurrence: ONE launch, 38 co-resident blocks ----
// r1 handshake structure, but the consumer spin uses RELAXED agent loads +
// ONE acquire fence per step (after the barrier). The old acquire-per-poll
// invalidated L1/L2 at poll rate (gfx950 non-coherent per-XCD L2), flushing
// xs/h/weight lines continuously -> 73MB FETCH and ~2.5x modeled step time.
__launch_bounds__(256, 1)
__global__ void k_lstm(const float* __restrict__ wihf, const float* __restrict__ whhf,
                       const float* __restrict__ bihf, const float* __restrict__ bhhf,
                       const float* __restrict__ wihb, const float* __restrict__ whhb,
                       const float* __restrict__ bihb, const float* __restrict__ bhhb,
                       char* __restrict__ ws) {
  const int dir  = blockIdx.x / NW;
  const int wg   = blockIdx.x % NW;
  const int h0   = wg * 16;
  const int tid  = threadIdx.x;
  const int w    = tid >> 6;
  const int lane = tid & 63;
  const int mhat = w & 1;
  const int khalf= w >> 1;
  const int nl   = lane & 15;
  const int quad = lane >> 4;
  const int hg   = h0 + nl;                 // 0..303
  const bool hvalid = hg < H_;

  const float* Wih = dir ? wihb : wihf;
  const float* Whh = dir ? whhb : whhf;
  const float* Bih = dir ? bihb : bihf;
  const float* Bhh = dir ? bhhb : bhhf;

  const short* xs = (const short*)(ws + XS_OFF);
  short* hb = (short*)(ws + HB_OFF);
  unsigned int* hist = (unsigned int*)(ws + HIST_OFF);   // 304 dwords per (t,b) row
  int* arr  = (int*)(ws + ARR_OFF);

  __shared__ short sh_xd[2][B_*328];        // double-buffered x tile
  __shared__ short sh_h[B_*328];
  __shared__ float red[2*4*64*4];
  __shared__ float shl[B_*17];              // fp32 h of this WG's 16 dims

  // ---- one-time: build weight B-fragments from fp32 into registers ----
  s8v wf[2][4][5];
  #pragma unroll
  for (int mat = 0; mat < 2; ++mat) {
    const float* W = mat ? Whh : Wih;
    #pragma unroll
    for (int nt = 0; nt < 4; ++nt) {
      const long rowbase = (long)(nt * H_ + hg) * H_;
      #pragma unroll
      for (int kci = 0; kci < 5; ++kci) {
        int kb = (khalf*5 + kci)*32 + quad*8;
        s8v v; v[0]=0;v[1]=0;v[2]=0;v[3]=0;v[4]=0;v[5]=0;v[6]=0;v[7]=0;
        if (hvalid) {
          #pragma unroll
          for (int half = 0; half < 2; ++half) {
            int k0 = kb + half*4;
            if (k0 + 4 <= H_) {
              f4v q = *(const f4v*)(W + rowbase + k0);    // 16B aligned
              v[half*4+0] = f2b(q[0]);
              v[half*4+1] = f2b(q[1]);
              v[half*4+2] = f2b(q[2]);
              v[half*4+3] = f2b(q[3]);
            } else {
              #pragma unroll
              for (int j = 0; j < 4; ++j) {
                int k = k0 + j;
                if (k < H_) v[half*4+j] = f2b(W[rowbase + k]);
              }
            }
          }
        }
        wf[mat][nt][kci] = v;
      }
    }
  }

  float bias[4];
  #pragma unroll
  for (int nt = 0; nt < 4; ++nt)
    bias[nt] = hvalid ? (Bih[nt*H_ + hg] + Bhh[nt*H_ + hg]) : 0.f;

  float creg[4] = {0.f, 0.f, 0.f, 0.f};     // c-state lives in registers
  const int arow = (mhat*16 + nl) * 328 + quad * 8;

  // loop-invariant staging offsets (thread -> (b,kg) chunk mapping)
  int soff[5], loff[5];
  #pragma unroll
  for (int i = 0; i < 5; ++i) {
    int u = tid + i*256;
    int b = u / 40, kg = u % 40;
    soff[i] = b*HP  + kg*8;                 // global shorts offset
    loff[i] = b*328 + kg*8;                 // LDS shorts offset (padded)
  }

  // prologue: stage x(t(0)) into buffer 0
  {
    const int t0 = dir ? (S_ - 1) : 0;
    const short* xsrc = xs + (long)t0 * B_ * HP;
    #pragma unroll
    for (int i = 0; i < 5; ++i)
      *(s8v*)&sh_xd[0][loff[i]] = *(const s8v*)&xsrc[soff[i]];
  }
  __syncthreads();

  for (int s = 0; s < S_; ++s) {
    const int t = dir ? (S_ - 1 - s) : s;
    const short* xcur = &sh_xd[s & 1][0];

    f4v acc[4];
    #pragma unroll
    for (int nt = 0; nt < 4; ++nt) { acc[nt][0]=0.f; acc[nt][1]=0.f; acc[nt][2]=0.f; acc[nt][3]=0.f; }

    // x-GEMM from pre-staged buffer (no exposed load latency)
    #pragma unroll
    for (int kci = 0; kci < 5; ++kci) {
      s8v a = *(const s8v*)&xcur[arow + (khalf*5 + kci)*32];
      #pragma unroll
      for (int nt = 0; nt < 4; ++nt)
        acc[nt] = __builtin_amdgcn_mfma_f32_16x16x32_bf16(a, wf[0][nt][kci], acc[nt], 0, 0, 0);
    }

    // issue x(t(s+1)) loads NOW: flight time hides under spin + h-stage + h-GEMM
    s8v xl[5];
    if (s + 1 < S_) {
      const int tn = dir ? (S_ - 2 - s) : (s + 1);
      const short* xsrc = xs + (long)tn * B_ * HP;
      #pragma unroll
      for (int i = 0; i < 5; ++i)
        xl[i] = *(const s8v*)&xsrc[soff[i]];
    }

    // wait: RELAXED polls (no per-iteration cache invalidation)
    if (s > 0 && tid < NW) {
      const int* fl = &arr[(dir*NW + tid)*16];
      while (__hip_atomic_load(fl, __ATOMIC_RELAXED, __HIP_MEMORY_SCOPE_AGENT) < s) { }
    }
    __syncthreads();                               // B: flags seen by all
    // ONE acquire fence per step: release-store -> relaxed-load-observed ->
    // acquire-fence establishes synchronizes-with; plain h loads below are fresh.
    __builtin_amdgcn_fence(__ATOMIC_ACQUIRE, "agent");

    // stage h(s) from ping-pong slot s&1 (plain vector loads, post-fence)
    {
      const short* hsrc = hb + (long)(dir*2 + (s & 1)) * B_ * HP;
      #pragma unroll
      for (int i = 0; i < 5; ++i)
        *(s8v*)&sh_h[loff[i]] = *(const s8v*)&hsrc[soff[i]];
    }
    __syncthreads();                               // C: sh_h ready

    #pragma unroll
    for (int kci = 0; kci < 5; ++kci) {
      s8v a = *(const s8v*)&sh_h[arow + (khalf*5 + kci)*32];
      #pragma unroll
      for (int nt = 0; nt < 4; ++nt)
        acc[nt] = __builtin_amdgcn_mfma_f32_16x16x32_bf16(a, wf[1][nt][kci], acc[nt], 0, 0, 0);
    }

    // K-half reduction
    if (khalf == 1) {
      #pragma unroll
      for (int nt = 0; nt < 4; ++nt)
        *(f4v*)&red[((mhat*4 + nt)*64 + lane)*4] = acc[nt];
    }
    __syncthreads();                               // D

    if (khalf == 0) {
      #pragma unroll
      for (int nt = 0; nt < 4; ++nt) {
        f4v o = *(const f4v*)&red[((mhat*4 + nt)*64 + lane)*4];
        acc[nt][0]+=o[0]; acc[nt][1]+=o[1]; acc[nt][2]+=o[2]; acc[nt][3]+=o[3];
      }
      #pragma unroll
      for (int r = 0; r < 4; ++r) {
        int b = mhat*16 + quad*4 + r;
        float gi = acc[0][r] + bias[0];
        float gf = acc[1][r] + bias[1];
        float gg = acc[2][r] + bias[2];
        float go = acc[3][r] + bias[3];
        float c  = sigf(gf) * creg[r] + sigf(gi) * tanh_f(gg);
        float h  = sigf(go) * tanh_f(c);
        creg[r] = c;
        shl[b*17 + nl] = h;                        // LDS only; publish below
      }
    }
    // write prefetched x(t(s+1)) into the other buffer (vmcnt long since satisfied)
    if (s + 1 < S_) {
      short* xnxt = &sh_xd[(s + 1) & 1][0];
      #pragma unroll
      for (int i = 0; i < 5; ++i)
        *(s8v*)&xnxt[loff[i]] = xl[i];
    }
    __syncthreads();                               // E: shl ready, x writes drained

    // publish h(s+1) (agent-atomic dwords) + history (plain dwords)
    {
      int b = tid >> 3, j = tid & 7;               // 32 rows x 8 dword-cols
      float fa = shl[b*17 + 2*j];
      float fb = shl[b*17 + 2*j + 1];
      unsigned int pack = (unsigned int)(unsigned short)f2b(fa) |
                          ((unsigned int)(unsigned short)f2b(fb) << 16);
      unsigned int* dsti = (unsigned int*)(hb + (long)(dir*2 + ((s+1) & 1)) * B_ * HP);
      __hip_atomic_store(&dsti[b*160 + (h0 >> 1) + j], pack,
                         __ATOMIC_RELAXED, __HIP_MEMORY_SCOPE_AGENT);
      hist[((long)t * B_ + b) * 304 + dir*152 + (h0 >> 1) + j] = pack;
    }
    __syncthreads();                               // F: vmcnt drained -> stores visible
    if (s + 1 < S_ && tid == 0)
      __hip_atomic_store(&arr[(dir*NW + wg)*16], s + 1,
                         __ATOMIC_RELEASE, __HIP_MEMORY_SCOPE_AGENT);
  }
}

// ---- logits + softmax + emit from h history ----
__global__ void k_logits(const int* __restrict__ y,
                         const float* __restrict__ lin_w, const float* __restrict__ lin_b,
                         char* __restrict__ ws, float* __restrict__ out) {
  __shared__ float lw[600*10];                     // lw[j*10+tg] = lin_w[tg][j], broadcast-friendly
  const unsigned int* hist = (const unsigned int*)(ws + HIST_OFF);
  float* em    = (float*)(ws + EM_OFF);
  float* emtag = (float*)(ws + EMTAG_OFF);
  int tid = threadIdx.x;
  for (int i = tid; i < 600*TAGS; i += 256) {
    int j = i / TAGS, tg = i % TAGS;
    lw[j*10 + tg] = lin_w[tg*600 + j];
  }
  __syncthreads();

  int g = blockIdx.x * 256 + tid;                  // 8192
  int b = g & 31, t = g >> 5;
  const unsigned int* hrow = hist + ((long)t * B_ + b) * 304;

  float lg[TAGS];
  #pragma unroll
  for (int tg = 0; tg < TAGS; ++tg) lg[tg] = lin_b[tg];

  for (int jd = 0; jd < 150; ++jd) {               // dir0: cols 0..299
    unsigned int v = hrow[jd];
    float ha = b2f(v & 0xffffu), hc = b2f(v >> 16);
    int j0 = 2*jd;
    #pragma unroll
    for (int tg = 0; tg < TAGS; ++tg)
      lg[tg] += ha * lw[j0*10 + tg] + hc * lw[(j0+1)*10 + tg];
  }
  for (int jd = 0; jd < 150; ++jd) {               // dir1: cols 300..599
    unsigned int v = hrow[152 + jd];
    float ha = b2f(v & 0xffffu), hc = b2f(v >> 16);
    int j0 = 300 + 2*jd;
    #pragma unroll
    for (int tg = 0; tg < TAGS; ++tg)
      lg[tg] += ha * lw[j0*10 + tg] + hc * lw[(j0+1)*10 + tg];
  }

  float m = lg[0];
  #pragma unroll
  for (int tg = 1; tg < TAGS; ++tg) m = fmaxf(m, lg[tg]);
  float p[TAGS]; float sum = 0.f;
  #pragma unroll
  for (int tg = 0; tg < TAGS; ++tg) { p[tg] = __expf(lg[tg] - m); sum += p[tg]; }
  float inv = 1.f / sum;

  int yy = y[b*S_ + t];
  int sel = (yy != -1) ? yy : 0;
  float et = 0.f;
  #pragma unroll
  for (int tg = 0; tg < TAGS; ++tg) {
    float pv = p[tg] * inv;
    out[((long)b*S_ + t)*TAGS + tg] = pv;          // FP32 output
    em[((long)t*B_ + b)*TAGS + tg] = pv;
    if (tg == sel) et = pv;
  }
  emtag[t*B_ + b] = et;
}

// ---- CRF: gold score + forward algorithm + loss (256 threads, strided) ----
__global__ void k_crf(const int* __restrict__ y,
                      const float* __restrict__ start_t, const float* __restrict__ end_t,
                      const float* __restrict__ trans,
                      char* __restrict__ ws, float* __restrict__ out) {
  __shared__ float tr[81], st[TAGS], en[TAGS];
  __shared__ float alpha[2][B_][12];
  __shared__ float resS[B_], resD[B_];
  const float* em    = (const float*)(ws + EM_OFF);
  const float* emtag = (const float*)(ws + EMTAG_OFF);
  int tid = threadIdx.x;
  if (tid < 81) tr[tid] = trans[tid];
  if (tid < TAGS) { st[tid] = start_t[tid]; en[tid] = end_t[tid]; }
  __syncthreads();

  for (int it = tid; it < B_*TAGS; it += 256) {
    int b = it / TAGS, j = it % TAGS;
    alpha[0][b][j] = st[j] + em[(0*B_ + b)*TAGS + j];
  }

  if (tid < B_) {
    int b = tid;
    int y0 = y[b*S_]; bool m0 = (y0 != -1); int tg0 = m0 ? y0 : 0;
    float score = st[tg0] + emtag[0*B_ + b];
    int cnt = m0 ? 1 : 0;
    int prev = tg0;
    for (int t = 1; t < S_; ++t) {
      int yt = y[b*S_ + t]; bool mt = (yt != -1); int tg = mt ? yt : 0;
      float mf = mt ? 1.f : 0.f;
      score += (tr[prev*TAGS + tg] + emtag[t*B_ + b]) * mf;
      prev = tg;
      cnt += mt ? 1 : 0;
    }
    int li = cnt - 1; if (li < 0) li = 0;
    int yl = y[b*S_ + li]; int tgl = (yl != -1) ? yl : 0;
    score += en[tgl];
    resS[b] = score;
  }
  __syncthreads();

  for (int t = 1; t < S_; ++t) {
    int pb = (t-1) & 1, cb2 = t & 1;
    for (int it = tid; it < B_*TAGS; it += 256) {
      int b = it / TAGS, j = it % TAGS;
      float a[TAGS]; float m = -1e30f;
      #pragma unroll
      for (int i = 0; i < TAGS; ++i) { a[i] = alpha[pb][b][i] + tr[i*TAGS + j]; m = fmaxf(m, a[i]); }
      float ssum = 0.f;
      #pragma unroll
      for (int i = 0; i < TAGS; ++i) ssum += __expf(a[i] - m);
      float v = m + __logf(ssum) + em[((long)t*B_ + b)*TAGS + j];
      bool mt = (y[b*S_ + t] != -1);
      alpha[cb2][b][j] = mt ? v : alpha[pb][b][j];
    }
    __syncthreads();
  }

  int fb = (S_-1) & 1;
  if (tid < B_) {
    int b = tid;
    float a[TAGS]; float m = -1e30f;
    #pragma unroll
    for (int i = 0; i < TAGS; ++i) { a[i] = alpha[fb][b][i] + en[i]; m = fmaxf(m, a[i]); }
    float ssum = 0.f;
    #pragma unroll
    for (int i = 0; i < TAGS; ++i) ssum += __expf(a[i] - m);
    resD[b] = m + __logf(ssum);
  }
  __syncthreads();
  if (tid == 0) {
    float llh = 0.f;
    for (int bb = 0; bb < B_; ++bb) llh += resS[bb] - resD[bb];
    out[LOSS_IDX] = -llh;                          // FP32 loss at float element 73728
  }
}

extern "C" void kernel_launch(void* const* d_in, const int* in_sizes, int n_in,
                              void* d_out, int out_size, void* d_ws, size_t ws_size,
                              hipStream_t stream) {
  const int* x = (const int*)d_in[0];
  const int* y = (const int*)d_in[1];
  const float* emb   = (const float*)d_in[2];
  const float* wihf  = (const float*)d_in[3];
  const float* whhf  = (const float*)d_in[4];
  const float* bihf  = (const float*)d_in[5];
  const float* bhhf  = (const float*)d_in[6];
  const float* wihb  = (const float*)d_in[7];
  const float* whhb  = (const float*)d_in[8];
  const float* bihb  = (const float*)d_in[9];
  const float* bhhb  = (const float*)d_in[10];
  const float* lin_w = (const float*)d_in[11];
  const float* lin_b = (const float*)d_in[12];
  const float* sta   = (const float*)d_in[13];
  const float* endt  = (const float*)d_in[14];
  const float* trans = (const float*)d_in[15];
  char* ws = (char*)d_ws;
  float* out = (float*)d_out;                      // reference outputs are FP32

  const long n_init = (long)S_*B_*80 + 2L*2*B_*HP/4 + 2L*NW*16;
  int grid_init = (int)((n_init + 255) / 256);
  k_init<<<grid_init, 256, 0, stream>>>(x, emb, ws);
  k_lstm<<<2*NW, 256, 0, stream>>>(wihf, whhf, bihf, bhhf,
                                   wihb, whhb, bihb, bhhb, ws);
  k_logits<<<(B_*S_)/256, 256, 0, stream>>>(y, lin_w, lin_b, ws, out);
  k_crf<<<1, 256, 0, stream>>>(y, sta, endt, trans, ws, out);
}

// Round 7
// 1072.006 us; speedup vs baseline: 1.5784x; 1.5784x over previous
//
#include <hip/hip_runtime.h>
#include <hip/hip_bf16.h>

typedef __attribute__((ext_vector_type(8))) short s8v;
typedef __attribute__((ext_vector_type(4))) short s4v;
typedef __attribute__((ext_vector_type(4))) float f4v;

#define B_   32
#define S_   256
#define H_   300
#define HP   320
#define NW   19
#define TAGS 9

// workspace layout (~14.9 MB; proven >=16.3 MB writable)
#define XS_OFF    0                      // bf16 staged embeddings: 256*32*320*2 = 5242880 B
#define HB_OFF    5242880                // bf16 h ping-pong: 2dir*2slot*32*320*2 = 81920 B
#define HIST_OFF  5324800                // bf16 h history: 256*32*608*2 = 9961472 B
#define EM_OFF    15286272               // fp32 emissions: 256*32*9*4 = 294912 B
#define EMTAG_OFF 15581184               // fp32: 256*32*4 = 32768 B
#define ARR_OFF   15613952               // per-WG flags: 2*NW*16 ints (64B apart) = 2432 B
#define REG_OFF   15616384               // XCD registration: ids 2*NW ints + cnt[2] (384 B)

#define LOSS_IDX  ((long)B_*S_*TAGS)     // float element 73728

__device__ __forceinline__ short f2b(float f) {
  unsigned int u = __builtin_bit_cast(unsigned int, f);
  u = (u + 0x7FFFu + ((u >> 16) & 1u)) >> 16;      // RNE fp32 -> bf16
  return (short)u;
}
__device__ __forceinline__ float b2f(unsigned int lo16) {
  return __builtin_bit_cast(float, lo16 << 16);
}
__device__ __forceinline__ float sigf(float x) { return 1.f / (1.f + __expf(-x)); }
__device__ __forceinline__ float tanh_f(float x) {
  x = fminf(fmaxf(x, -15.f), 15.f);
  float e = __expf(-2.f * x);
  return (1.f - e) / (1.f + e);
}

// ---- init: gather emb->bf16 xs (padded K 320), zero h ping-pong + flags + reg ----
__global__ void k_init(const int* __restrict__ x, const float* __restrict__ emb,
                       char* __restrict__ ws) {
  short* xs = (short*)(ws + XS_OFF);
  short* hb = (short*)(ws + HB_OFF);
  int* arr  = (int*)(ws + ARR_OFF);
  long u = (long)blockIdx.x * blockDim.x + threadIdx.x;
  const long N1 = (long)S_ * B_ * 80;              // s4v units of xs
  if (u < N1) {
    int kg = (int)(u % 80);
    long tb = u / 80;
    int b = (int)(tb % B_);
    int t = (int)(tb / B_);
    int k = kg * 4;
    s4v v; v[0]=0; v[1]=0; v[2]=0; v[3]=0;
    if (k + 4 <= H_) {                             // emb rows are 16B aligned (300%4==0)
      int row = x[b * S_ + t];
      f4v q = *(const f4v*)(emb + (long)row * H_ + k);
      v[0]=f2b(q[0]); v[1]=f2b(q[1]); v[2]=f2b(q[2]); v[3]=f2b(q[3]);
    }
    *(s4v*)(xs + ((long)t * B_ + b) * HP + k) = v;
    return;
  }
  u -= N1;
  const long N2 = 2L * 2 * B_ * HP / 4;            // s4v units of hb
  if (u < N2) {
    s4v z; z[0]=0; z[1]=0; z[2]=0; z[3]=0;
    *(s4v*)(hb + u * 4) = z;
    return;
  }
  u -= N2;
  if (u < 704) arr[u] = 0;                         // flags (608) + registration (96)
}

// ---- persistent BiLSTM recurrence ----
// Grid = 152; only blockIdx%8==0 (dir0) and %8==4 (dir1) survive, idx = bid>>3.
// Round-robin bid->XCD heuristic puts each direction's 19 WGs on ONE XCD.
// Runtime-verified via HW_REG_XCC_ID; if all 19 ids match -> FAST path:
//   h publish = plain stores (write-through L1->L2), flag = plain-scope
//   global_atomic_swap (executes at XCD L2), poll = global_atomic_or 0 sc0
//   (L2 RMW), h reload = sc0 loads (L1-bypass, L2-hit). No agent ops, no LLC
//   round-trips, no cache invalidation in the steady-state loop.
// If ids differ -> fall back to the r1 agent-scope protocol (correct anywhere).
__launch_bounds__(256, 1)
__global__ void k_lstm(const float* __restrict__ wihf, const float* __restrict__ whhf,
                       const float* __restrict__ bihf, const float* __restrict__ bhhf,
                       const float* __restrict__ wihb, const float* __restrict__ whhb,
                       const float* __restrict__ bihb, const float* __restrict__ bhhb,
                       char* __restrict__ ws) {
  const int slot = blockIdx.x & 7;
  const int idx  = blockIdx.x >> 3;
  if ((slot != 0 && slot != 4) || idx >= NW) return;
  const int dir  = (slot == 4) ? 1 : 0;
  const int wg   = idx;
  const int h0   = wg * 16;
  const int tid  = threadIdx.x;
  const int w    = tid >> 6;
  const int lane = tid & 63;
  const int mhat = w & 1;
  const int khalf= w >> 1;
  const int nl   = lane & 15;
  const int quad = lane >> 4;
  const int hg   = h0 + nl;                 // 0..303
  const bool hvalid = hg < H_;

  const float* Wih = dir ? wihb : wihf;
  const float* Whh = dir ? whhb : whhf;
  const float* Bih = dir ? bihb : bihf;
  const float* Bhh = dir ? bhhb : bhhf;

  const short* xs = (const short*)(ws + XS_OFF);
  short* hb = (short*)(ws + HB_OFF);
  unsigned int* hist = (unsigned int*)(ws + HIST_OFF);   // 304 dwords per (t,b) row
  int* arr  = (int*)(ws + ARR_OFF);
  int* ids  = (int*)(ws + REG_OFF);
  int* cnt  = (int*)(ws + REG_OFF + 256);   // cnt[dir] at +dir*64 B

  __shared__ short sh_xd[2][B_*328];        // double-buffered x tile
  __shared__ short sh_h[B_*328];
  __shared__ float red[2*4*64*4];
  __shared__ float shl[B_*17];              // fp32 h of this WG's 16 dims
  __shared__ int sh_fast;

  // ---- register this block's XCD id (heuristic check; fallback keeps correctness)
  unsigned xcd;
  asm volatile("s_getreg_b32 %0, hwreg(HW_REG_XCC_ID)" : "=s"(xcd));
  if (tid == 0) {
    __hip_atomic_store(&ids[dir*NW + wg], (int)(xcd + 1),
                       __ATOMIC_RELAXED, __HIP_MEMORY_SCOPE_AGENT);
    __hip_atomic_fetch_add(&cnt[dir*16], 1, __ATOMIC_ACQ_REL, __HIP_MEMORY_SCOPE_AGENT);
  }

  // ---- one-time: build weight B-fragments from fp32 into registers ----
  s8v wf[2][4][5];
  #pragma unroll
  for (int mat = 0; mat < 2; ++mat) {
    const float* W = mat ? Whh : Wih;
    #pragma unroll
    for (int nt = 0; nt < 4; ++nt) {
      const long rowbase = (long)(nt * H_ + hg) * H_;
      #pragma unroll
      for (int kci = 0; kci < 5; ++kci) {
        int kb = (khalf*5 + kci)*32 + quad*8;
        s8v v; v[0]=0;v[1]=0;v[2]=0;v[3]=0;v[4]=0;v[5]=0;v[6]=0;v[7]=0;
        if (hvalid) {
          #pragma unroll
          for (int half = 0; half < 2; ++half) {
            int k0 = kb + half*4;
            if (k0 + 4 <= H_) {
              f4v q = *(const f4v*)(W + rowbase + k0);    // 16B aligned
              v[half*4+0] = f2b(q[0]);
              v[half*4+1] = f2b(q[1]);
              v[half*4+2] = f2b(q[2]);
              v[half*4+3] = f2b(q[3]);
            } else {
              #pragma unroll
              for (int j = 0; j < 4; ++j) {
                int k = k0 + j;
                if (k < H_) v[half*4+j] = f2b(W[rowbase + k]);
              }
            }
          }
        }
        wf[mat][nt][kci] = v;
      }
    }
  }

  float bias[4];
  #pragma unroll
  for (int nt = 0; nt < 4; ++nt)
    bias[nt] = hvalid ? (Bih[nt*H_ + hg] + Bhh[nt*H_ + hg]) : 0.f;

  // ---- decide fast/slow path (uniform across the direction group)
  if (tid == 0) {
    while (__hip_atomic_load(&cnt[dir*16], __ATOMIC_ACQUIRE, __HIP_MEMORY_SCOPE_AGENT) < NW) {}
    int ok = 1; const int mine = (int)(xcd + 1);
    for (int i = 0; i < NW; ++i)
      ok &= (__hip_atomic_load(&ids[dir*NW + i], __ATOMIC_RELAXED,
                               __HIP_MEMORY_SCOPE_AGENT) == mine);
    sh_fast = ok;
  }

  float creg[4] = {0.f, 0.f, 0.f, 0.f};     // c-state lives in registers
  const int arow = (mhat*16 + nl) * 328 + quad * 8;

  // loop-invariant staging offsets (thread -> (b,kg) chunk mapping)
  int soff[5], loff[5];
  #pragma unroll
  for (int i = 0; i < 5; ++i) {
    int u = tid + i*256;
    int b = u / 40, kg = u % 40;
    soff[i] = b*HP  + kg*8;                 // global shorts offset
    loff[i] = b*328 + kg*8;                 // LDS shorts offset (padded)
  }

  // prologue: stage x(t(0)) into buffer 0
  {
    const int t0 = dir ? (S_ - 1) : 0;
    const short* xsrc = xs + (long)t0 * B_ * HP;
    #pragma unroll
    for (int i = 0; i < 5; ++i)
      *(s8v*)&sh_xd[0][loff[i]] = *(const s8v*)&xsrc[soff[i]];
  }
  __syncthreads();                           // also publishes sh_fast
  const bool FAST = (sh_fast != 0);

  for (int s = 0; s < S_; ++s) {
    const int t = dir ? (S_ - 1 - s) : s;
    const short* xcur = &sh_xd[s & 1][0];

    f4v acc[4];
    #pragma unroll
    for (int nt = 0; nt < 4; ++nt) { acc[nt][0]=0.f; acc[nt][1]=0.f; acc[nt][2]=0.f; acc[nt][3]=0.f; }

    // x-GEMM from pre-staged buffer (no exposed load latency)
    #pragma unroll
    for (int kci = 0; kci < 5; ++kci) {
      s8v a = *(const s8v*)&xcur[arow + (khalf*5 + kci)*32];
      #pragma unroll
      for (int nt = 0; nt < 4; ++nt)
        acc[nt] = __builtin_amdgcn_mfma_f32_16x16x32_bf16(a, wf[0][nt][kci], acc[nt], 0, 0, 0);
    }

    // issue x(t(s+1)) loads NOW: flight time hides under spin + h-stage + h-GEMM
    s8v xl[5];
    if (s + 1 < S_) {
      const int tn = dir ? (S_ - 2 - s) : (s + 1);
      const short* xsrc = xs + (long)tn * B_ * HP;
      #pragma unroll
      for (int i = 0; i < 5; ++i)
        xl[i] = *(const s8v*)&xsrc[soff[i]];
    }

    // wait: 19 parallel spins on independent cachelines
    if (s > 0 && tid < NW) {
      if (FAST) {
        // L2-local atomic RMW poll (no sc1 -> executes at this XCD's L2)
        unsigned long long fl = (unsigned long long)&arr[(dir*NW + tid)*16];
        unsigned v;
        do {
          asm volatile("global_atomic_or %0, %1, %2, off sc0\n\ts_waitcnt vmcnt(0)"
                       : "=&v"(v) : "v"(fl), "v"(0u) : "memory");
        } while ((int)v < s);
      } else {
        const int* fl = &arr[(dir*NW + tid)*16];
        while (__hip_atomic_load(fl, __ATOMIC_ACQUIRE, __HIP_MEMORY_SCOPE_AGENT) < s) { }
      }
    }
    __syncthreads();                               // B: flags seen by all

    // stage h(s) from ping-pong slot s&1
    {
      const short* hsrc = hb + (long)(dir*2 + (s & 1)) * B_ * HP;
      if (FAST) {
        // sc0 loads: bypass L1, read this XCD's L2 (producers' write-through target)
        s8v r0, r1, r2, r3, r4;
        const void* p0 = &hsrc[soff[0]];
        const void* p1 = &hsrc[soff[1]];
        const void* p2 = &hsrc[soff[2]];
        const void* p3 = &hsrc[soff[3]];
        const void* p4 = &hsrc[soff[4]];
        asm volatile(
          "global_load_dwordx4 %0, %5, off sc0\n\t"
          "global_load_dwordx4 %1, %6, off sc0\n\t"
          "global_load_dwordx4 %2, %7, off sc0\n\t"
          "global_load_dwordx4 %3, %8, off sc0\n\t"
          "global_load_dwordx4 %4, %9, off sc0\n\t"
          "s_waitcnt vmcnt(0)"
          : "=&v"(r0), "=&v"(r1), "=&v"(r2), "=&v"(r3), "=&v"(r4)
          : "v"(p0), "v"(p1), "v"(p2), "v"(p3), "v"(p4)
          : "memory");
        *(s8v*)&sh_h[loff[0]] = r0;
        *(s8v*)&sh_h[loff[1]] = r1;
        *(s8v*)&sh_h[loff[2]] = r2;
        *(s8v*)&sh_h[loff[3]] = r3;
        *(s8v*)&sh_h[loff[4]] = r4;
      } else {
        #pragma unroll
        for (int i = 0; i < 5; ++i)
          *(s8v*)&sh_h[loff[i]] = *(const s8v*)&hsrc[soff[i]];
      }
    }
    __syncthreads();                               // C: sh_h ready

    #pragma unroll
    for (int kci = 0; kci < 5; ++kci) {
      s8v a = *(const s8v*)&sh_h[arow + (khalf*5 + kci)*32];
      #pragma unroll
      for (int nt = 0; nt < 4; ++nt)
        acc[nt] = __builtin_amdgcn_mfma_f32_16x16x32_bf16(a, wf[1][nt][kci], acc[nt], 0, 0, 0);
    }

    // K-half reduction
    if (khalf == 1) {
      #pragma unroll
      for (int nt = 0; nt < 4; ++nt)
        *(f4v*)&red[((mhat*4 + nt)*64 + lane)*4] = acc[nt];
    }
    __syncthreads();                               // D

    if (khalf == 0) {
      #pragma unroll
      for (int nt = 0; nt < 4; ++nt) {
        f4v o = *(const f4v*)&red[((mhat*4 + nt)*64 + lane)*4];
        acc[nt][0]+=o[0]; acc[nt][1]+=o[1]; acc[nt][2]+=o[2]; acc[nt][3]+=o[3];
      }
      #pragma unroll
      for (int r = 0; r < 4; ++r) {
        int b = mhat*16 + quad*4 + r;
        float gi = acc[0][r] + bias[0];
        float gf = acc[1][r] + bias[1];
        float gg = acc[2][r] + bias[2];
        float go = acc[3][r] + bias[3];
        float c  = sigf(gf) * creg[r] + sigf(gi) * tanh_f(gg);
        float h  = sigf(go) * tanh_f(c);
        creg[r] = c;
        shl[b*17 + nl] = h;                        // LDS only; publish below
      }
    }
    // write prefetched x(t(s+1)) into the other buffer (vmcnt long since satisfied)
    if (s + 1 < S_) {
      short* xnxt = &sh_xd[(s + 1) & 1][0];
      #pragma unroll
      for (int i = 0; i < 5; ++i)
        *(s8v*)&xnxt[loff[i]] = xl[i];
    }
    __syncthreads();                               // E: shl ready, x writes drained

    // publish h(s+1) + history
    {
      int b = tid >> 3, j = tid & 7;               // 32 rows x 8 dword-cols
      float fa = shl[b*17 + 2*j];
      float fb = shl[b*17 + 2*j + 1];
      unsigned int pack = (unsigned int)(unsigned short)f2b(fa) |
                          ((unsigned int)(unsigned short)f2b(fb) << 16);
      unsigned int* dsti = (unsigned int*)(hb + (long)(dir*2 + ((s+1) & 1)) * B_ * HP);
      if (FAST) {
        dsti[b*160 + (h0 >> 1) + j] = pack;        // plain: write-through L1 -> XCD L2
      } else {
        __hip_atomic_store(&dsti[b*160 + (h0 >> 1) + j], pack,
                           __ATOMIC_RELAXED, __HIP_MEMORY_SCOPE_AGENT);
      }
      hist[((long)t * B_ + b) * 304 + dir*152 + (h0 >> 1) + j] = pack;
    }
    __syncthreads();                               // F: vmcnt drained -> stores in L2/LLC
    if (s + 1 < S_ && tid == 0) {
      if (FAST) {
        unsigned long long fl = (unsigned long long)&arr[(dir*NW + wg)*16];
        asm volatile("global_atomic_swap %0, %1, off"
                     :: "v"(fl), "v"((unsigned)(s + 1)) : "memory");
      } else {
        __hip_atomic_store(&arr[(dir*NW + wg)*16], s + 1,
                           __ATOMIC_RELEASE, __HIP_MEMORY_SCOPE_AGENT);
      }
    }
  }
}

// ---- logits + softmax + emit from h history ----
__global__ void k_logits(const int* __restrict__ y,
                         const float* __restrict__ lin_w, const float* __restrict__ lin_b,
                         char* __restrict__ ws, float* __restrict__ out) {
  __shared__ float lw[600*10];                     // lw[j*10+tg] = lin_w[tg][j], broadcast-friendly
  const unsigned int* hist = (const unsigned int*)(ws + HIST_OFF);
  float* em    = (float*)(ws + EM_OFF);
  float* emtag = (float*)(ws + EMTAG_OFF);
  int tid = threadIdx.x;
  for (int i = tid; i < 600*TAGS; i += 256) {
    int j = i / TAGS, tg = i % TAGS;
    lw[j*10 + tg] = lin_w[tg*600 + j];
  }
  __syncthreads();

  int g = blockIdx.x * 256 + tid;                  // 8192
  int b = g & 31, t = g >> 5;
  const unsigned int* hrow = hist + ((long)t * B_ + b) * 304;

  float lg[TAGS];
  #pragma unroll
  for (int tg = 0; tg < TAGS; ++tg) lg[tg] = lin_b[tg];

  for (int jd = 0; jd < 150; ++jd) {               // dir0: cols 0..299
    unsigned int v = hrow[jd];
    float ha = b2f(v & 0xffffu), hc = b2f(v >> 16);
    int j0 = 2*jd;
    #pragma unroll
    for (int tg = 0; tg < TAGS; ++tg)
      lg[tg] += ha * lw[j0*10 + tg] + hc * lw[(j0+1)*10 + tg];
  }
  for (int jd = 0; jd < 150; ++jd) {               // dir1: cols 300..599
    unsigned int v = hrow[152 + jd];
    float ha = b2f(v & 0xffffu), hc = b2f(v >> 16);
    int j0 = 300 + 2*jd;
    #pragma unroll
    for (int tg = 0; tg < TAGS; ++tg)
      lg[tg] += ha * lw[j0*10 + tg] + hc * lw[(j0+1)*10 + tg];
  }

  float m = lg[0];
  #pragma unroll
  for (int tg = 1; tg < TAGS; ++tg) m = fmaxf(m, lg[tg]);
  float p[TAGS]; float sum = 0.f;
  #pragma unroll
  for (int tg = 0; tg < TAGS; ++tg) { p[tg] = __expf(lg[tg] - m); sum += p[tg]; }
  float inv = 1.f / sum;

  int yy = y[b*S_ + t];
  int sel = (yy != -1) ? yy : 0;
  float et = 0.f;
  #pragma unroll
  for (int tg = 0; tg < TAGS; ++tg) {
    float pv = p[tg] * inv;
    out[((long)b*S_ + t)*TAGS + tg] = pv;          // FP32 output
    em[((long)t*B_ + b)*TAGS + tg] = pv;
    if (tg == sel) et = pv;
  }
  emtag[t*B_ + b] = et;
}

// ---- CRF: gold score + forward algorithm + loss (256 threads, strided) ----
__global__ void k_crf(const int* __restrict__ y,
                      const float* __restrict__ start_t, const float* __restrict__ end_t,
                      const float* __restrict__ trans,
                      char* __restrict__ ws, float* __restrict__ out) {
  __shared__ float tr[81], st[TAGS], en[TAGS];
  __shared__ float alpha[2][B_][12];
  __shared__ float resS[B_], resD[B_];
  const float* em    = (const float*)(ws + EM_OFF);
  const float* emtag = (const float*)(ws + EMTAG_OFF);
  int tid = threadIdx.x;
  if (tid < 81) tr[tid] = trans[tid];
  if (tid < TAGS) { st[tid] = start_t[tid]; en[tid] = end_t[tid]; }
  __syncthreads();

  for (int it = tid; it < B_*TAGS; it += 256) {
    int b = it / TAGS, j = it % TAGS;
    alpha[0][b][j] = st[j] + em[(0*B_ + b)*TAGS + j];
  }

  if (tid < B_) {
    int b = tid;
    int y0 = y[b*S_]; bool m0 = (y0 != -1); int tg0 = m0 ? y0 : 0;
    float score = st[tg0] + emtag[0*B_ + b];
    int cnt = m0 ? 1 : 0;
    int prev = tg0;
    for (int t = 1; t < S_; ++t) {
      int yt = y[b*S_ + t]; bool mt = (yt != -1); int tg = mt ? yt : 0;
      float mf = mt ? 1.f : 0.f;
      score += (tr[prev*TAGS + tg] + emtag[t*B_ + b]) * mf;
      prev = tg;
      cnt += mt ? 1 : 0;
    }
    int li = cnt - 1; if (li < 0) li = 0;
    int yl = y[b*S_ + li]; int tgl = (yl != -1) ? yl : 0;
    score += en[tgl];
    resS[b] = score;
  }
  __syncthreads();

  for (int t = 1; t < S_; ++t) {
    int pb = (t-1) & 1, cb2 = t & 1;
    for (int it = tid; it < B_*TAGS; it += 256) {
      int b = it / TAGS, j = it % TAGS;
      float a[TAGS]; float m = -1e30f;
      #pragma unroll
      for (int i = 0; i < TAGS; ++i) { a[i] = alpha[pb][b][i] + tr[i*TAGS + j]; m = fmaxf(m, a[i]); }
      float ssum = 0.f;
      #pragma unroll
      for (int i = 0; i < TAGS; ++i) ssum += __expf(a[i] - m);
      float v = m + __logf(ssum) + em[((long)t*B_ + b)*TAGS + j];
      bool mt = (y[b*S_ + t] != -1);
      alpha[cb2][b][j] = mt ? v : alpha[pb][b][j];
    }
    __syncthreads();
  }

  int fb = (S_-1) & 1;
  if (tid < B_) {
    int b = tid;
    float a[TAGS]; float m = -1e30f;
    #pragma unroll
    for (int i = 0; i < TAGS; ++i) { a[i] = alpha[fb][b][i] + en[i]; m = fmaxf(m, a[i]); }
    float ssum = 0.f;
    #pragma unroll
    for (int i = 0; i < TAGS; ++i) ssum += __expf(a[i] - m);
    resD[b] = m + __logf(ssum);
  }
  __syncthreads();
  if (tid == 0) {
    float llh = 0.f;
    for (int bb = 0; bb < B_; ++bb) llh += resS[bb] - resD[bb];
    out[LOSS_IDX] = -llh;                          // FP32 loss at float element 73728
  }
}

extern "C" void kernel_launch(void* const* d_in, const int* in_sizes, int n_in,
                              void* d_out, int out_size, void* d_ws, size_t ws_size,
                              hipStream_t stream) {
  const int* x = (const int*)d_in[0];
  const int* y = (const int*)d_in[1];
  const float* emb   = (const float*)d_in[2];
  const float* wihf  = (const float*)d_in[3];
  const float* whhf  = (const float*)d_in[4];
  const float* bihf  = (const float*)d_in[5];
  const float* bhhf  = (const float*)d_in[6];
  const float* wihb  = (const float*)d_in[7];
  const float* whhb  = (const float*)d_in[8];
  const float* bihb  = (const float*)d_in[9];
  const float* bhhb  = (const float*)d_in[10];
  const float* lin_w = (const float*)d_in[11];
  const float* lin_b = (const float*)d_in[12];
  const float* sta   = (const float*)d_in[13];
  const float* endt  = (const float*)d_in[14];
  const float* trans = (const float*)d_in[15];
  char* ws = (char*)d_ws;
  float* out = (float*)d_out;                      // reference outputs are FP32

  const long n_init = (long)S_*B_*80 + 2L*2*B_*HP/4 + 704;
  int grid_init = (int)((n_init + 255) / 256);
  k_init<<<grid_init, 256, 0, stream>>>(x, emb, ws);
  k_lstm<<<152, 256, 0, stream>>>(wihf, whhf, bihf, bhhf,
                                  wihb, whhb, bihb, bhhb, ws);
  k_logits<<<(B_*S_)/256, 256, 0, stream>>>(y, lin_w, lin_b, ws, out);
  k_crf<<<1, 256, 0, stream>>>(y, sta, endt, trans, ws, out);
}